// Round 8
// baseline (124.006 us; speedup 1.0000x reference)
//
#include <hip/hip_runtime.h>
#include <hip/hip_bf16.h>

// Problem: B=32, S=512, P=512, D=768
//   M = B*S = 16384 tokens, N = P = 512 prototypes, K = D = 768
// out[0 .. M*N)            = distances  ||x_m - p_n||^2  (fp32)
// out[M*N .. M*N + N*K)    = prototypes (fp32 passthrough)
//
// R8 = R5 barrier-free skeleton + latency/conflict fixes:
//   - 1024 threads (16 waves) per block -> 4 waves/SIMD (was 2): 2x latency hiding.
//   - wave tile 64x32 (acc 32 VGPRs) so 16 waves share one 64-row A stripe;
//     B bytes per block unchanged (whole 768 KB B read once per block from L2).
//   - B global->VGPR prefetch depth 2 (rolling 3-slot buffer) to cover ~300cyc L2 lat.
//   - ASTR 778 (row stride = 389 dwords = 5 mod 32 banks): A-frag ds_read_b128
//     <=2-way bank aliasing (free) instead of 8-way at 776.
//   - A stripe staged ONCE (fp32 -> exact fp32 x_sq -> bf16 -> LDS); ONE barrier.

#define M_TOK 16384
#define N_PROT 512
#define K_DIM 768
#define BK 32
#define NCH (K_DIM / BK)     // 24
#define ASTR 778             // padded LDS row stride in bf16 units (= 389 dwords)

typedef __attribute__((ext_vector_type(4))) float f32x4;
typedef __attribute__((ext_vector_type(8))) short bf16x8;

__device__ inline unsigned short f2bf(float f) {
    // round-to-nearest-even on the bit pattern (finite inputs)
    unsigned int u = __float_as_uint(f);
    u += 0x7fffu + ((u >> 16) & 1u);
    return (unsigned short)(u >> 16);
}

// One wave per prototype row: bf16 convert + ||p||^2 + fp32 passthrough copy.
__global__ __launch_bounds__(256) void prep_b(
    const float* __restrict__ p,
    unsigned short* __restrict__ b_bf, float* __restrict__ p_sq,
    float* __restrict__ proto_out)
{
    const int row  = blockIdx.x * 4 + (threadIdx.x >> 6);
    const int lane = threadIdx.x & 63;

    const float4* src4 = (const float4*)(p + (size_t)row * K_DIM);
    unsigned short* dst = b_bf + (size_t)row * K_DIM;
    float4* pout4 = (float4*)(proto_out + (size_t)row * K_DIM);

    float ssum = 0.0f;
#pragma unroll
    for (int j = 0; j < 3; ++j) {        // 192 float4 per row / 64 lanes
        const int idx = lane + j * 64;
        float4 v = src4[idx];
        ssum += v.x * v.x + v.y * v.y + v.z * v.z + v.w * v.w;
        ushort4 b;
        b.x = f2bf(v.x); b.y = f2bf(v.y); b.z = f2bf(v.z); b.w = f2bf(v.w);
        ((ushort4*)dst)[idx] = b;
        pout4[idx] = v;
    }
#pragma unroll
    for (int off = 32; off > 0; off >>= 1) ssum += __shfl_down(ssum, off);
    if (lane == 0) p_sq[row] = ssum;
}

__global__ __launch_bounds__(1024) void dist_main(
    const float* __restrict__ X,             // [M,K] fp32 tokens
    const unsigned short* __restrict__ Bb,   // [N,K] bf16 prototypes (ws)
    const float* __restrict__ p_sq,          // [N] fp32
    float* __restrict__ out)                 // [M,N] fp32 distances
{
    __shared__ unsigned short lds_a[64 * ASTR];   // 99,584 B: full-K A stripe
    __shared__ float lds_xsq[64];

    const int tid  = threadIdx.x;
    const int wave = tid >> 6;           // 0..15
    const int lane = tid & 63;
    const int bm   = blockIdx.x << 6;    // 64-row A stripe
    const int wn   = wave << 5;          // this wave's 32-col slice of N
    const int quad = lane >> 4;          // 0..3
    const int l16  = lane & 15;

    // ---- one-time A staging: fp32 -> (x_sq, bf16 LDS) ----
    // 1024 threads: 64 rows x 16 float4-cols; 12 iterations cover 192 float4/row.
    const int ar = tid >> 4;             // 0..63 row
    const int ac = tid & 15;             // float4 col base
    const float* aptr = X + (size_t)(bm + ar) * K_DIM;
    float asq = 0.0f;
#pragma unroll
    for (int j = 0; j < 12; ++j) {
        const int c4 = ac + 16 * j;      // float4 index 0..191
        float4 v = *(const float4*)(aptr + (size_t)c4 * 4);
        asq += v.x * v.x + v.y * v.y + v.z * v.z + v.w * v.w;
        ushort4 u;
        u.x = f2bf(v.x); u.y = f2bf(v.y); u.z = f2bf(v.z); u.w = f2bf(v.w);
        *(ushort4*)&lds_a[ar * ASTR + c4 * 4] = u;
    }
#pragma unroll
    for (int off = 1; off < 16; off <<= 1) asq += __shfl_xor(asq, off);
    if (ac == 0) lds_xsq[ar] = asq;

    __syncthreads();   // the ONLY barrier

    // ---- barrier-free K-loop: wave tile 64 x 32, 4x2 MFMA frags ----
    const f32x4 zero = {0.0f, 0.0f, 0.0f, 0.0f};
    f32x4 acc[4][2];
#pragma unroll
    for (int mt = 0; mt < 4; ++mt)
#pragma unroll
        for (int nt = 0; nt < 2; ++nt) acc[mt][nt] = zero;

    // per-lane B fragment pointer: row (wn + nt*16 + l16), 16B chunk at quad*8
    const unsigned short* bp = Bb + (size_t)(wn + l16) * K_DIM + quad * 8;

    // rolling 3-slot prefetch buffer, depth 2
    bf16x8 bb[3][2];
#pragma unroll
    for (int nt = 0; nt < 2; ++nt) {
        bb[0][nt] = *(const bf16x8*)(bp + (size_t)(nt * 16) * K_DIM);
        bb[1][nt] = *(const bf16x8*)(bp + (size_t)(nt * 16) * K_DIM + BK);
    }

#pragma unroll
    for (int kc = 0; kc < NCH; ++kc) {
        const int slot = kc % 3;
        if (kc + 2 < NCH) {
            const int ns = (kc + 2) % 3;
#pragma unroll
            for (int nt = 0; nt < 2; ++nt)
                bb[ns][nt] = *(const bf16x8*)
                    (bp + (size_t)(nt * 16) * K_DIM + (kc + 2) * BK);
        }

        bf16x8 af[4];
#pragma unroll
        for (int mt = 0; mt < 4; ++mt)
            af[mt] = *(const bf16x8*)
                &lds_a[(mt * 16 + l16) * ASTR + kc * BK + quad * 8];

#pragma unroll
        for (int mt = 0; mt < 4; ++mt)
#pragma unroll
            for (int nt = 0; nt < 2; ++nt)
                acc[mt][nt] = __builtin_amdgcn_mfma_f32_16x16x32_bf16(
                    af[mt], bb[slot][nt], acc[mt][nt], 0, 0, 0);
    }

    // ---- epilogue: C/D layout col = lane&15, row = quad*4 + i ----
    float ps[2];
#pragma unroll
    for (int nt = 0; nt < 2; ++nt) ps[nt] = p_sq[wn + nt * 16 + l16];

#pragma unroll
    for (int mt = 0; mt < 4; ++mt) {
#pragma unroll
        for (int i = 0; i < 4; ++i) {
            const int lr = mt * 16 + quad * 4 + i;   // local row 0..63
            const float xs = lds_xsq[lr];
            float* orow = out + (size_t)(bm + lr) * N_PROT + wn + l16;
#pragma unroll
            for (int nt = 0; nt < 2; ++nt)
                orow[nt * 16] = xs + ps[nt] - 2.0f * acc[mt][nt][i];
        }
    }
}

extern "C" void kernel_launch(void* const* d_in, const int* in_sizes, int n_in,
                              void* d_out, int out_size, void* d_ws, size_t ws_size,
                              hipStream_t stream) {
    const float* inputs = (const float*)d_in[0];   // [32,512,768] fp32
    const float* protos = (const float*)d_in[1];   // [512,768]    fp32
    float* out = (float*)d_out;
    float* proto_out = out + (size_t)M_TOK * N_PROT;   // second tuple element

    // ws layout: b_bf 512*768*2 = 786,432 B ; p_sq 512*4 = 2,048 B
    char* ws = (char*)d_ws;
    unsigned short* b_bf = (unsigned short*)ws;
    float* p_sq = (float*)(ws + 786432);

    prep_b<<<128, 256, 0, stream>>>(protos, b_bf, p_sq, proto_out);
    dist_main<<<M_TOK / 64, 1024, 0, stream>>>(inputs, b_bf, p_sq, out);
}